// Round 1
// baseline (122.570 us; speedup 1.0000x reference)
//
#include <hip/hip_runtime.h>
#include <math.h>

#define B_ 2
#define M_ 384
#define N_ 384
// ker table: 10 (padded theta) x 4 (r) cells, each 16x16 (oy x f)
#define NCELL 40
#define SSTRIDE 17   // pad 16 -> 17 to spread LDS banks

__global__ __launch_bounds__(256) void build_table_kernel(
    const float* __restrict__ kern, float* __restrict__ table) {
  // kern: [C_OUT=8][C_IN=8][NUM_R=4][NUM_THETA=8][2][2]
  // table: [cell=tw*4+xr][f=i*2+x][oy=o*2+y]  (so contraction reads coalesce over oy)
  int cell = blockIdx.x;          // 0..39
  int t = threadIdx.x;            // 0..255 == f*16 + oy
  int f = t >> 4, oy = t & 15;
  int tw = cell >> 2, xr = cell & 3;
  int th = (tw == 0) ? 7 : ((tw == 9) ? 0 : (tw - 1));  // circular theta pad
  int o = oy >> 1, y = oy & 1, i = f >> 1, x = f & 1;
  int src = ((((o * 8 + i) * 4 + xr) * 8 + th) * 2 + y) * 2 + x;
  table[cell * 256 + t] = kern[src];
}

__global__ __launch_bounds__(256) void equiconv_kernel(
    const float* __restrict__ field,   // [B][N][2]
    const float* __restrict__ center,  // [B][M][2]
    const float* __restrict__ feat,    // [B][N][8][2] -> 16 per n
    const float* __restrict__ mask,    // [B][N][1]
    const float* __restrict__ table,   // [40][16][16]
    float* __restrict__ out) {         // [B][M][8][2] -> 16 per (b,m)
  __shared__ float S[NCELL * SSTRIDE];
  __shared__ float psi_s;
  __shared__ float partial[16][17];

  int t = threadIdx.x;
  int bm = blockIdx.x;
  int b = bm / M_;

  for (int j = t; j < NCELL * SSTRIDE; j += 256) S[j] = 0.f;
  if (t == 0) psi_s = 0.f;
  __syncthreads();

  float cx = center[bm * 2 + 0];
  float cy = center[bm * 2 + 1];
  const float invR = 1.0f / 1.5f;
  const float four_over_pi = 4.0f / 3.14159265358979323846f;

  for (int n = t; n < N_; n += 256) {
    int fn = b * N_ + n;
    float fx = field[fn * 2 + 0];
    float fy = field[fn * 2 + 1];
    float rx = (fx - cx) * invR;
    float ry = (fy - cy) * invR;
    float r2 = rx * rx + ry * ry;
    float onem = 1.f - r2;
    float att = onem * onem * onem;
    if (att <= 0.f) continue;          // relu -> 0, no contribution at all
    att *= mask[fn];
    if (att == 0.f) continue;

    atomicAdd(&psi_s, att);

    float r = sqrtf(r2 + 1e-9f);
    float theta = (rx == 0.f && ry == 0.f) ? 0.f : atan2f(ry, rx);
    // ix = ((gx+1)*4-1)/2 with gx=2r-1  ->  4r - 0.5
    // iy = ((gy+1)*10-1)/2 with gy=theta/pi*0.8 -> 4*theta/pi + 4.5
    float ix = 4.f * r - 0.5f;
    float iy = theta * four_over_pi + 4.5f;
    float x0f = floorf(ix), y0f = floorf(iy);
    float wx = ix - x0f, wy = iy - y0f;
    int x0 = (int)x0f, y0 = (int)y0f;
    float wx0 = 1.f - wx, wx1 = wx;
    float wy0 = 1.f - wy, wy1 = wy;

    const float4* fp = (const float4*)(feat + fn * 16);
    float4 f0 = fp[0], f1 = fp[1], f2 = fp[2], f3 = fp[3];

#define DO_CORNER(X, Y, W)                                                  \
    do {                                                                    \
      int xc = (X), yc = (Y);                                               \
      if ((unsigned)xc <= 3u && (unsigned)yc <= 9u) {                       \
        float s = att * (W);                                                \
        float* Sp = &S[(yc * 4 + xc) * SSTRIDE];                            \
        atomicAdd(Sp + 0, s * f0.x);  atomicAdd(Sp + 1, s * f0.y);          \
        atomicAdd(Sp + 2, s * f0.z);  atomicAdd(Sp + 3, s * f0.w);          \
        atomicAdd(Sp + 4, s * f1.x);  atomicAdd(Sp + 5, s * f1.y);          \
        atomicAdd(Sp + 6, s * f1.z);  atomicAdd(Sp + 7, s * f1.w);          \
        atomicAdd(Sp + 8, s * f2.x);  atomicAdd(Sp + 9, s * f2.y);          \
        atomicAdd(Sp + 10, s * f2.z); atomicAdd(Sp + 11, s * f2.w);         \
        atomicAdd(Sp + 12, s * f3.x); atomicAdd(Sp + 13, s * f3.y);         \
        atomicAdd(Sp + 14, s * f3.z); atomicAdd(Sp + 15, s * f3.w);         \
      }                                                                     \
    } while (0)

    DO_CORNER(x0,     y0,     wx0 * wy0);
    DO_CORNER(x0 + 1, y0,     wx1 * wy0);
    DO_CORNER(x0,     y0 + 1, wx0 * wy1);
    DO_CORNER(x0 + 1, y0 + 1, wx1 * wy1);
#undef DO_CORNER
  }
  __syncthreads();

  // contraction: out[oy] = sum_cell sum_f table[cell][f][oy] * S[cell][f]
  int oy = t & 15, g = t >> 4;
  float acc = 0.f;
  for (int cell = g; cell < NCELL; cell += 16) {
    const float* tp = table + cell * 256 + oy;
    const float* Sp = &S[cell * SSTRIDE];
#pragma unroll
    for (int f = 0; f < 16; ++f) acc += tp[f * 16] * Sp[f];
  }
  partial[g][oy] = acc;
  __syncthreads();

  if (t < 16) {
    float sum = 0.f;
#pragma unroll
    for (int gg = 0; gg < 16; ++gg) sum += partial[gg][t];
    float psi = psi_s;
    if (psi == 0.f) psi = 1.f;
    out[bm * 16 + t] = sum / psi;
  }
}

extern "C" void kernel_launch(void* const* d_in, const int* in_sizes, int n_in,
                              void* d_out, int out_size, void* d_ws, size_t ws_size,
                              hipStream_t stream) {
  (void)in_sizes; (void)n_in; (void)out_size; (void)ws_size;
  const float* field  = (const float*)d_in[0];
  const float* center = (const float*)d_in[1];
  const float* feat   = (const float*)d_in[2];
  const float* mask   = (const float*)d_in[3];
  const float* kern   = (const float*)d_in[4];
  float* out = (float*)d_out;
  float* table = (float*)d_ws;  // 40*256 floats = 40960 B

  build_table_kernel<<<dim3(NCELL), dim3(256), 0, stream>>>(kern, table);
  equiconv_kernel<<<dim3(B_ * M_), dim3(256), 0, stream>>>(
      field, center, feat, mask, table, out);
}